// Round 2
// baseline (93.919 us; speedup 1.0000x reference)
//
#include <hip/hip_runtime.h>
#include <hip/hip_bf16.h>

// CubicalLayer gather: out[i] = X[row_i * 4096 + col_i], N_IDX = 524288 pairs.
// Round 2: 4 gathers/thread for MLP. Two int4 idx loads (32 B/lane),
// 4 independent random gathers in flight, one float4 coalesced store.
// N_IDX = 524288 is divisible by 4, so no tail handling needed (guard kept
// for safety anyway).

__global__ __launch_bounds__(256) void cubical_gather4_kernel(
    const float* __restrict__ X,
    const int4* __restrict__ idx,   // 2 consecutive (row,col) pairs per int4
    float4* __restrict__ out,
    int n4)                          // number of float4 outputs = N_IDX/4
{
    int i = blockIdx.x * blockDim.x + threadIdx.x;
    if (i < n4) {
        int4 a = idx[2 * i];        // pairs 0,1  (coalesced 16B)
        int4 b = idx[2 * i + 1];    // pairs 2,3  (coalesced 16B)
        // 4 independent gathers -> compiler issues all before s_waitcnt,
        // hiding L2/L3 hit latency (~200-400 cyc) 4-deep per thread.
        float4 r;
        r.x = X[(a.x << 12) + a.y];
        r.y = X[(a.z << 12) + a.w];
        r.z = X[(b.x << 12) + b.y];
        r.w = X[(b.z << 12) + b.w];
        out[i] = r;                 // coalesced 16B store
    }
}

extern "C" void kernel_launch(void* const* d_in, const int* in_sizes, int n_in,
                              void* d_out, int out_size, void* d_ws, size_t ws_size,
                              hipStream_t stream) {
    const float* X   = (const float*)d_in[0];
    const int4*  idx = (const int4*)d_in[1];
    float4* out = (float4*)d_out;

    int n  = in_sizes[1] / 2;       // 524288 gather points
    int n4 = n / 4;                 // 131072 float4 outputs
    int block = 256;
    int grid = (n4 + block - 1) / block;   // 512 blocks = 2048 waves
    cubical_gather4_kernel<<<grid, block, 0, stream>>>(X, idx, out, n4);
}